// Round 5
// baseline (2683.265 us; speedup 1.0000x reference)
//
#include <hip/hip_runtime.h>
#include <cstdint>
#include <cstddef>

// GraphWeather processor: 4 layers of edge-message MLP + scatter-add + node-update MLP.
// Key restructuring: edge GEMMs factored through linearity into node-level GEMMs:
//   P = x@Wm1[:128], Q = x@Wm1[128:]  (node GEMM)   pre_edge = P[dst]+Q[src]+bm1
//   aggr = segsum(relu(LN(pre)))@Wm2 + (indeg+1)*bm2  (node GEMM after scatter of h)
// => per-edge work is gather + LN + scatter only; all GEMMs are [50K,128]@[128,128] fp32.

#define THREADS 256
constexpr int HIDC   = 128;
constexpr int NNODES = 50000;
constexpr int NEDGES = 500000;
constexpr int TM     = 32;    // rows per block tile
constexpr int LDSTR  = 132;   // padded LDS row stride (floats): kills staging bank conflicts

typedef int edge_t;  // JAX x64-disabled => int32 buffers ("integer -> const int*")

__device__ __forceinline__ float4 ld4(const float* p) { return *reinterpret_cast<const float4*>(p); }
__device__ __forceinline__ void  st4(float* p, float4 v) { *reinterpret_cast<float4*>(p) = v; }
__device__ __forceinline__ void  zero4(float4 a[4]) {
#pragma unroll
  for (int j = 0; j < 4; ++j) a[j] = make_float4(0.f, 0.f, 0.f, 0.f);
}

// Stage a TM x 128 tile (row-major global, stride 128) into LDS (stride LDSTR).
__device__ __forceinline__ void stage32(float* dst, const float* __restrict__ src, int row0, int M)
{
  const int tid = threadIdx.x;
#pragma unroll
  for (int i = 0; i < 4; ++i) {
    int f  = i * THREADS + tid;       // 0..1023 float4 slots
    int r  = f >> 5;
    int c4 = (f & 31) * 4;
    int gr = row0 + r; if (gr > M - 1) gr = M - 1;   // clamp tail (stores are guarded later)
    st4(dst + r * LDSTR + c4, ld4(src + (size_t)gr * HIDC + c4));
  }
}

// acc[j] += A_tile[4*tr+j][:] @ W[:, 4*tc .. 4*tc+3]   (K=128)
// A reads: half-wave-uniform address => LDS broadcast, conflict-free.
// W reads: lanes 0..31 cover 512B contiguous => fully coalesced, L2 resident.
__device__ __forceinline__ void gemm128(const float* A, const float* __restrict__ W,
                                        int tr, int tc, float4 acc[4])
{
  const float* a0 = A + (4 * tr + 0) * LDSTR;
  const float* a1 = A + (4 * tr + 1) * LDSTR;
  const float* a2 = A + (4 * tr + 2) * LDSTR;
  const float* a3 = A + (4 * tr + 3) * LDSTR;
  const float* wp = W + 4 * tc;
#pragma unroll 2
  for (int k = 0; k < 128; k += 4) {
    float4 va0 = ld4(a0 + k), va1 = ld4(a1 + k), va2 = ld4(a2 + k), va3 = ld4(a3 + k);
    float av[4][4] = {{va0.x, va0.y, va0.z, va0.w},
                      {va1.x, va1.y, va1.z, va1.w},
                      {va2.x, va2.y, va2.z, va2.w},
                      {va3.x, va3.y, va3.z, va3.w}};
#pragma unroll
    for (int kk = 0; kk < 4; ++kk) {
      float4 w = ld4(wp + (size_t)(k + kk) * HIDC);
#pragma unroll
      for (int j = 0; j < 4; ++j) {
        acc[j].x = fmaf(av[j][kk], w.x, acc[j].x);
        acc[j].y = fmaf(av[j][kk], w.y, acc[j].y);
        acc[j].z = fmaf(av[j][kk], w.z, acc[j].z);
        acc[j].w = fmaf(av[j][kk], w.w, acc[j].w);
      }
    }
  }
}

// ---------------- kernels ----------------

// cnt[n] += 1 per edge with dst == n (as float; +1 self-loop added at use site)
__global__ __launch_bounds__(THREADS) void count_kernel(const edge_t* __restrict__ ei, float* cnt, int E)
{
  int e = blockIdx.x * THREADS + threadIdx.x;
  if (e < E) atomicAdd(cnt + ei[E + e], 1.0f);
}

// PQ[n, 0:128] = x[n] @ Wm1[:128,:];  PQ[n, 128:256] = x[n] @ Wm1[128:,:]
__global__ __launch_bounds__(THREADS) void pq_kernel(const float* __restrict__ x,
                                                     const float* __restrict__ Wm1,
                                                     float* __restrict__ PQ, int M)
{
  __shared__ float A[TM * LDSTR];
  const int row0 = blockIdx.x * TM;
  stage32(A, x, row0, M);
  __syncthreads();
  const int tc = threadIdx.x & 31, tr = threadIdx.x >> 5;

  float4 acc[4];
  zero4(acc);
  gemm128(A, Wm1, tr, tc, acc);                       // P half
#pragma unroll
  for (int j = 0; j < 4; ++j) {
    int r = row0 + 4 * tr + j;
    if (r < M) st4(PQ + (size_t)r * 256 + 4 * tc, acc[j]);
  }
  zero4(acc);
  gemm128(A, Wm1 + 128 * HIDC, tr, tc, acc);          // Q half
#pragma unroll
  for (int j = 0; j < 4; ++j) {
    int r = row0 + 4 * tr + j;
    if (r < M) st4(PQ + (size_t)r * 256 + 128 + 4 * tc, acc[j]);
  }
}

// One wave per message row (E real edges + N self-loops):
//   pre = P[dst] + Q[src] + bm1; h = relu(LN(pre)); atomicAdd H[dst] += h
__global__ __launch_bounds__(THREADS) void edge_kernel(const float* __restrict__ PQ,
                                                       const edge_t* __restrict__ ei,
                                                       const float* __restrict__ bm1,
                                                       const float* __restrict__ g,
                                                       const float* __restrict__ b,
                                                       float* __restrict__ Hbuf,
                                                       int E, int N)
{
  const int wid  = (blockIdx.x * THREADS + threadIdx.x) >> 6;
  const int lane = threadIdx.x & 63;
  if (wid >= E + N) return;
  int d, s;
  if (wid < E) { s = (int)ei[wid]; d = (int)ei[E + wid]; }
  else         { d = s = wid - E; }

  float2 vp = *reinterpret_cast<const float2*>(PQ + (size_t)d * 256 + 2 * lane);
  float2 vq = *reinterpret_cast<const float2*>(PQ + (size_t)s * 256 + 128 + 2 * lane);
  float2 bb = reinterpret_cast<const float2*>(bm1)[lane];
  float x0 = vp.x + vq.x + bb.x;
  float x1 = vp.y + vq.y + bb.y;

  float sum = x0 + x1, sq = x0 * x0 + x1 * x1;
#pragma unroll
  for (int m = 32; m >= 1; m >>= 1) { sum += __shfl_xor(sum, m); sq += __shfl_xor(sq, m); }
  float mu   = sum * (1.0f / 128.0f);
  float var  = sq * (1.0f / 128.0f) - mu * mu;
  float rstd = rsqrtf(var + 1e-5f);

  float2 gg = reinterpret_cast<const float2*>(g)[lane];
  float2 bl = reinterpret_cast<const float2*>(b)[lane];
  float h0 = fmaxf(0.f, (x0 - mu) * rstd * gg.x + bl.x);
  float h1 = fmaxf(0.f, (x1 - mu) * rstd * gg.y + bl.y);

  float* hp = Hbuf + (size_t)d * HIDC + 2 * lane;
  atomicAdd(hp,     h0);
  atomicAdd(hp + 1, h1);
}

// Fused node update:
//   aggr = H@Wm2 + (cnt+1)*bm2
//   pre2 = x@Wu1[:128] + aggr@Wu1[128:] + bu1 ; h2 = relu(LN(pre2))
//   x_new = h2@Wu2 + bu2      (and PQ_next = x_new@Wm1_next for layers 0..2)
__global__ __launch_bounds__(THREADS) void fused_update(
    const float* __restrict__ x,   const float* __restrict__ H,
    const float* __restrict__ cnt,
    const float* __restrict__ Wm2, const float* __restrict__ bm2,
    const float* __restrict__ Wu1, const float* __restrict__ bu1,
    const float* __restrict__ gu,  const float* __restrict__ bun,
    const float* __restrict__ Wu2, const float* __restrict__ bu2,
    float* __restrict__ xout,
    const float* __restrict__ Wm1n, float* __restrict__ PQn,
    int M)
{
  __shared__ float A[TM * LDSTR];
  __shared__ float B[TM * LDSTR];
  const int row0 = blockIdx.x * TM;
  const int tc = threadIdx.x & 31, tr = threadIdx.x >> 5;

  // ---- P1: aggr = H@Wm2 + (cnt+1)*bm2  -> B ----
  stage32(A, H, row0, M);
  __syncthreads();
  float4 acc[4];
  zero4(acc);
  gemm128(A, Wm2, tr, tc, acc);
  {
    float4 bm2v = ld4(bm2 + 4 * tc);
#pragma unroll
    for (int j = 0; j < 4; ++j) {
      int r = row0 + 4 * tr + j; if (r > M - 1) r = M - 1;
      float c = cnt[r] + 1.0f;
      acc[j].x = fmaf(c, bm2v.x, acc[j].x);
      acc[j].y = fmaf(c, bm2v.y, acc[j].y);
      acc[j].z = fmaf(c, bm2v.z, acc[j].z);
      acc[j].w = fmaf(c, bm2v.w, acc[j].w);
    }
  }
#pragma unroll
  for (int j = 0; j < 4; ++j) st4(B + (4 * tr + j) * LDSTR + 4 * tc, acc[j]);
  __syncthreads();               // A fully read, B fully written
  stage32(A, x, row0, M);
  __syncthreads();

  // ---- P2: pre2 = x@Wu1_top + aggr@Wu1_bot + bu1 ; h2 = relu(LN(pre2)) ----
  zero4(acc);
  gemm128(A, Wu1, tr, tc, acc);
  gemm128(B, Wu1 + 128 * HIDC, tr, tc, acc);
  {
    float4 b1 = ld4(bu1 + 4 * tc);
    float4 gv = ld4(gu  + 4 * tc);
    float4 bv = ld4(bun + 4 * tc);
#pragma unroll
    for (int j = 0; j < 4; ++j) {
      float4 v = acc[j];
      v.x += b1.x; v.y += b1.y; v.z += b1.z; v.w += b1.w;
      float s = v.x + v.y + v.z + v.w;
      float q = v.x * v.x + v.y * v.y + v.z * v.z + v.w * v.w;
#pragma unroll
      for (int m = 16; m >= 1; m >>= 1) { s += __shfl_xor(s, m); q += __shfl_xor(q, m); }
      float mu   = s * (1.0f / 128.0f);
      float var  = q * (1.0f / 128.0f) - mu * mu;
      float rstd = rsqrtf(var + 1e-5f);
      v.x = fmaxf(0.f, (v.x - mu) * rstd * gv.x + bv.x);
      v.y = fmaxf(0.f, (v.y - mu) * rstd * gv.y + bv.y);
      v.z = fmaxf(0.f, (v.z - mu) * rstd * gv.z + bv.z);
      v.w = fmaxf(0.f, (v.w - mu) * rstd * gv.w + bv.w);
      acc[j] = v;
    }
  }
  __syncthreads();               // all threads done reading B (aggr)
#pragma unroll
  for (int j = 0; j < 4; ++j) st4(B + (4 * tr + j) * LDSTR + 4 * tc, acc[j]);  // h2 -> B
  __syncthreads();

  // ---- P3: x_new = h2@Wu2 + bu2 ----
  zero4(acc);
  gemm128(B, Wu2, tr, tc, acc);
  {
    float4 b2 = ld4(bu2 + 4 * tc);
#pragma unroll
    for (int j = 0; j < 4; ++j) {
      acc[j].x += b2.x; acc[j].y += b2.y; acc[j].z += b2.z; acc[j].w += b2.w;
      int r = row0 + 4 * tr + j;
      if (r < M) st4(xout + (size_t)r * HIDC + 4 * tc, acc[j]);
    }
  }

  // ---- P4 (layers 0..2): PQ_next = x_new @ Wm1_next ----
  if (PQn != nullptr) {
#pragma unroll
    for (int j = 0; j < 4; ++j) st4(A + (4 * tr + j) * LDSTR + 4 * tc, acc[j]); // x_new -> A
    __syncthreads();
    float4 acc2[4];
    zero4(acc2);
    gemm128(A, Wm1n, tr, tc, acc2);
#pragma unroll
    for (int j = 0; j < 4; ++j) {
      int r = row0 + 4 * tr + j;
      if (r < M) st4(PQn + (size_t)r * 256 + 4 * tc, acc2[j]);
    }
    zero4(acc2);
    gemm128(A, Wm1n + 128 * HIDC, tr, tc, acc2);
#pragma unroll
    for (int j = 0; j < 4; ++j) {
      int r = row0 + 4 * tr + j;
      if (r < M) st4(PQn + (size_t)r * 256 + 128 + 4 * tc, acc2[j]);
    }
  }
}

// ---------------- launch ----------------

extern "C" void kernel_launch(void* const* d_in, const int* in_sizes, int n_in,
                              void* d_out, int out_size, void* d_ws, size_t ws_size,
                              hipStream_t stream)
{
  const float*  x_in = (const float*)d_in[0];
  const edge_t* ei   = (const edge_t*)d_in[1];
  const float*  Wm1  = (const float*)d_in[2];
  const float*  bm1  = (const float*)d_in[3];
  const float*  gm   = (const float*)d_in[4];
  const float*  bmn  = (const float*)d_in[5];
  const float*  Wm2  = (const float*)d_in[6];
  const float*  bm2  = (const float*)d_in[7];
  const float*  Wu1  = (const float*)d_in[8];
  const float*  bu1  = (const float*)d_in[9];
  const float*  gu   = (const float*)d_in[10];
  const float*  bun  = (const float*)d_in[11];
  const float*  Wu2  = (const float*)d_in[12];
  const float*  bu2  = (const float*)d_in[13];

  const int N = NNODES, E = NEDGES;

  char* ws = (char*)d_ws;
  float* PQ  = (float*)(ws + 0);            // N*256*4 = 51,200,000
  float* Hb  = (float*)(ws + 51200000);     // N*128*4 = 25,600,000
  float* xA  = (float*)(ws + 76800000);     // 25,600,000
  float* xB  = (float*)(ws + 102400000);    // 25,600,000
  float* cnt = (float*)(ws + 128000000);    // N*4

  const int gemmBlocks = (N + TM - 1) / TM;          // 1563
  const int edgeBlocks = (E + N + 3) / 4;            // 4 waves (messages) per block

  // in-degree counts (shared by all layers)
  hipMemsetAsync(cnt, 0, (size_t)N * 4, stream);
  count_kernel<<<(E + THREADS - 1) / THREADS, THREADS, 0, stream>>>(ei, cnt, E);

  // PQ for layer 0 from the input features
  pq_kernel<<<gemmBlocks, THREADS, 0, stream>>>(x_in, Wm1, PQ, N);

  const float* xc = x_in;
  float* xnext[4] = {xA, xB, xA, (float*)d_out};

  for (int l = 0; l < 4; ++l) {
    hipMemsetAsync(Hb, 0, (size_t)N * HIDC * 4, stream);
    edge_kernel<<<edgeBlocks, THREADS, 0, stream>>>(
        PQ, ei, bm1 + l * HIDC, gm + l * HIDC, bmn + l * HIDC, Hb, E, N);
    fused_update<<<gemmBlocks, THREADS, 0, stream>>>(
        xc, Hb, cnt,
        Wm2 + (size_t)l * HIDC * HIDC, bm2 + l * HIDC,
        Wu1 + (size_t)l * 256 * HIDC,  bu1 + l * HIDC,
        gu + l * HIDC, bun + l * HIDC,
        Wu2 + (size_t)l * HIDC * HIDC, bu2 + l * HIDC,
        xnext[l],
        (l < 3) ? (Wm1 + (size_t)(l + 1) * 256 * HIDC) : nullptr,
        (l < 3) ? PQ : nullptr,
        N);
    xc = xnext[l];
  }
}

// Round 8
// 1293.075 us; speedup vs baseline: 2.0751x; 2.0751x over previous
//
#include <hip/hip_runtime.h>
#include <cstdint>
#include <cstddef>

// GraphWeather processor: 4 layers of edge-message MLP + scatter-add + node-update MLP.
// Round 6/7/8: replaced atomic scatter (edge_kernel) with CSR gather-aggregate.
//   R5 counters: edge_kernel = 69% of time, WRITE_SIZE 563 MB (atomics write-through
//   to HBM at 1KB/row), only 23% HBM BW, 16% VALU -> atomic-bound.
//   Now: CSR build once per call; agg_kernel = one wave per dst node, registers
//   accumulate, single streaming write of H. (indeg+1) read from row_ptr.
// Factored GEMMs (unchanged): P=x@Wm1_top, Q=x@Wm1_bot node-level;
//   aggr = segsum(h)@Wm2 + (indeg+1)*bm2.

#define THREADS 256
constexpr int HIDC   = 128;
constexpr int NNODES = 50000;
constexpr int NEDGES = 500000;
constexpr int TM     = 32;    // rows per block tile
constexpr int LDSTR  = 132;   // padded LDS row stride (floats): kills staging bank conflicts

typedef int edge_t;  // JAX x64-disabled => int32 buffers

__device__ __forceinline__ float4 ld4(const float* p) { return *reinterpret_cast<const float4*>(p); }
__device__ __forceinline__ void  st4(float* p, float4 v) { *reinterpret_cast<float4*>(p) = v; }
__device__ __forceinline__ void  zero4(float4 a[4]) {
#pragma unroll
  for (int j = 0; j < 4; ++j) a[j] = make_float4(0.f, 0.f, 0.f, 0.f);
}

// Stage a TM x 128 tile (row-major global, stride 128) into LDS (stride LDSTR).
__device__ __forceinline__ void stage32(float* dst, const float* __restrict__ src, int row0, int M)
{
  const int tid = threadIdx.x;
#pragma unroll
  for (int i = 0; i < 4; ++i) {
    int f  = i * THREADS + tid;       // 0..1023 float4 slots
    int r  = f >> 5;
    int c4 = (f & 31) * 4;
    int gr = row0 + r; if (gr > M - 1) gr = M - 1;   // clamp tail (stores are guarded later)
    st4(dst + r * LDSTR + c4, ld4(src + (size_t)gr * HIDC + c4));
  }
}

// acc[j] += A_tile[4*tr+j][:] @ W[:, 4*tc .. 4*tc+3]   (K=128)
__device__ __forceinline__ void gemm128(const float* A, const float* __restrict__ W,
                                        int tr, int tc, float4 acc[4])
{
  const float* a0 = A + (4 * tr + 0) * LDSTR;
  const float* a1 = A + (4 * tr + 1) * LDSTR;
  const float* a2 = A + (4 * tr + 2) * LDSTR;
  const float* a3 = A + (4 * tr + 3) * LDSTR;
  const float* wp = W + 4 * tc;
#pragma unroll 2
  for (int k = 0; k < 128; k += 4) {
    float4 va0 = ld4(a0 + k), va1 = ld4(a1 + k), va2 = ld4(a2 + k), va3 = ld4(a3 + k);
    float av[4][4] = {{va0.x, va0.y, va0.z, va0.w},
                      {va1.x, va1.y, va1.z, va1.w},
                      {va2.x, va2.y, va2.z, va2.w},
                      {va3.x, va3.y, va3.z, va3.w}};
#pragma unroll
    for (int kk = 0; kk < 4; ++kk) {
      float4 w = ld4(wp + (size_t)(k + kk) * HIDC);
#pragma unroll
      for (int j = 0; j < 4; ++j) {
        acc[j].x = fmaf(av[j][kk], w.x, acc[j].x);
        acc[j].y = fmaf(av[j][kk], w.y, acc[j].y);
        acc[j].z = fmaf(av[j][kk], w.z, acc[j].z);
        acc[j].w = fmaf(av[j][kk], w.w, acc[j].w);
      }
    }
  }
}

// ---------------- CSR build ----------------

__global__ __launch_bounds__(THREADS) void count_kernel(const edge_t* __restrict__ ei,
                                                        int* __restrict__ deg, int E)
{
  int e = blockIdx.x * THREADS + threadIdx.x;
  if (e < E) atomicAdd(deg + ei[E + e], 1);
}

// Exclusive scan of deg[0..N) -> row_ptr[0..N], copy to fill_ptr. Single block, 1024 thr.
__global__ __launch_bounds__(1024) void scan_kernel(const int* __restrict__ deg,
                                                    int* __restrict__ row_ptr,
                                                    int* __restrict__ fill_ptr, int N)
{
  __shared__ int part[1024];
  const int t = threadIdx.x;
  const int chunk = (N + 1023) >> 10;
  const int beg = t * chunk;
  const int end = min(beg + chunk, N);
  int s = 0;
  for (int i = beg; i < end; ++i) s += deg[i];
  part[t] = s;
  __syncthreads();
  for (int off = 1; off < 1024; off <<= 1) {
    int v = (t >= off) ? part[t - off] : 0;
    __syncthreads();
    part[t] += v;
    __syncthreads();
  }
  int run = part[t] - s;                       // exclusive prefix
  for (int i = beg; i < end; ++i) {
    row_ptr[i] = run; fill_ptr[i] = run; run += deg[i];
  }
  if (t == 1023) row_ptr[N] = run;             // = E
}

__global__ __launch_bounds__(THREADS) void fill_kernel(const edge_t* __restrict__ ei,
                                                       int* __restrict__ fill_ptr,
                                                       int* __restrict__ adj, int E)
{
  int e = blockIdx.x * THREADS + threadIdx.x;
  if (e < E) {
    int s = (int)ei[e], d = (int)ei[E + e];
    int pos = atomicAdd(fill_ptr + d, 1);
    adj[pos] = s;
  }
}

// ---------------- compute kernels ----------------

// PQ[n, 0:128] = x[n] @ Wm1[:128,:];  PQ[n, 128:256] = x[n] @ Wm1[128:,:]
__global__ __launch_bounds__(THREADS) void pq_kernel(const float* __restrict__ x,
                                                     const float* __restrict__ Wm1,
                                                     float* __restrict__ PQ, int M)
{
  __shared__ float A[TM * LDSTR];
  const int row0 = blockIdx.x * TM;
  stage32(A, x, row0, M);
  __syncthreads();
  const int tc = threadIdx.x & 31, tr = threadIdx.x >> 5;

  float4 acc[4];
  zero4(acc);
  gemm128(A, Wm1, tr, tc, acc);                       // P half
#pragma unroll
  for (int j = 0; j < 4; ++j) {
    int r = row0 + 4 * tr + j;
    if (r < M) st4(PQ + (size_t)r * 256 + 4 * tc, acc[j]);
  }
  zero4(acc);
  gemm128(A, Wm1 + 128 * HIDC, tr, tc, acc);          // Q half
#pragma unroll
  for (int j = 0; j < 4; ++j) {
    int r = row0 + 4 * tr + j;
    if (r < M) st4(PQ + (size_t)r * 256 + 128 + 4 * tc, acc[j]);
  }
}

// One wave per dst node: acc = sum over {self + incoming edges} of
//   relu(LN(P[d] + Q[src] + bm1)); single write H[d].
__global__ __launch_bounds__(THREADS) void agg_kernel(const float* __restrict__ PQ,
                                                      const int* __restrict__ row_ptr,
                                                      const int* __restrict__ adj,
                                                      const float* __restrict__ bm1,
                                                      const float* __restrict__ g,
                                                      const float* __restrict__ b,
                                                      float* __restrict__ H, int N)
{
  const int d    = (blockIdx.x * THREADS + threadIdx.x) >> 6;
  const int lane = threadIdx.x & 63;
  if (d >= N) return;

  const float2 bb = reinterpret_cast<const float2*>(bm1)[lane];
  const float2 pv = *reinterpret_cast<const float2*>(PQ + (size_t)d * 256 + 2 * lane);
  const float bx = pv.x + bb.x, by = pv.y + bb.y;    // P[d]+bm1 hoisted
  const float2 gg = reinterpret_cast<const float2*>(g)[lane];
  const float2 bl = reinterpret_cast<const float2*>(b)[lane];

  const int beg = row_ptr[d];
  const int cnt = row_ptr[d + 1] - beg;

  // message i=0 is the self-loop (src = d); prefetch next Q row each iter
  float2 q = *reinterpret_cast<const float2*>(PQ + (size_t)d * 256 + 128 + 2 * lane);
  float a0 = 0.f, a1 = 0.f;
  for (int i = 0; i <= cnt; ++i) {
    float2 qn = make_float2(0.f, 0.f);
    if (i < cnt) {                                    // wave-uniform branch
      int s = adj[beg + i];
      qn = *reinterpret_cast<const float2*>(PQ + (size_t)s * 256 + 128 + 2 * lane);
    }
    float x0 = bx + q.x, x1 = by + q.y;
    float sum = x0 + x1, sq = x0 * x0 + x1 * x1;
#pragma unroll
    for (int m = 32; m >= 1; m >>= 1) { sum += __shfl_xor(sum, m); sq += __shfl_xor(sq, m); }
    float mu   = sum * (1.0f / 128.0f);
    float var  = sq * (1.0f / 128.0f) - mu * mu;
    float rstd = rsqrtf(var + 1e-5f);
    a0 += fmaxf(0.f, (x0 - mu) * rstd * gg.x + bl.x);
    a1 += fmaxf(0.f, (x1 - mu) * rstd * gg.y + bl.y);
    q = qn;
  }
  *reinterpret_cast<float2*>(H + (size_t)d * HIDC + 2 * lane) = make_float2(a0, a1);
}

// Fused node update:
//   aggr = H@Wm2 + (indeg+1)*bm2
//   pre2 = x@Wu1[:128] + aggr@Wu1[128:] + bu1 ; h2 = relu(LN(pre2))
//   x_new = h2@Wu2 + bu2      (and PQ_next = x_new@Wm1_next for layers 0..2)
__global__ __launch_bounds__(THREADS) void fused_update(
    const float* __restrict__ x,   const float* __restrict__ H,
    const int* __restrict__ rp,
    const float* __restrict__ Wm2, const float* __restrict__ bm2,
    const float* __restrict__ Wu1, const float* __restrict__ bu1,
    const float* __restrict__ gu,  const float* __restrict__ bun,
    const float* __restrict__ Wu2, const float* __restrict__ bu2,
    float* __restrict__ xout,
    const float* __restrict__ Wm1n, float* __restrict__ PQn,
    int M)
{
  __shared__ float A[TM * LDSTR];
  __shared__ float B[TM * LDSTR];
  const int row0 = blockIdx.x * TM;
  const int tc = threadIdx.x & 31, tr = threadIdx.x >> 5;

  // ---- P1: aggr = H@Wm2 + (indeg+1)*bm2  -> B ----
  stage32(A, H, row0, M);
  __syncthreads();
  float4 acc[4];
  zero4(acc);
  gemm128(A, Wm2, tr, tc, acc);
  {
    float4 bm2v = ld4(bm2 + 4 * tc);
#pragma unroll
    for (int j = 0; j < 4; ++j) {
      int r = row0 + 4 * tr + j; if (r > M - 1) r = M - 1;
      float c = (float)(rp[r + 1] - rp[r]) + 1.0f;
      acc[j].x = fmaf(c, bm2v.x, acc[j].x);
      acc[j].y = fmaf(c, bm2v.y, acc[j].y);
      acc[j].z = fmaf(c, bm2v.z, acc[j].z);
      acc[j].w = fmaf(c, bm2v.w, acc[j].w);
    }
  }
#pragma unroll
  for (int j = 0; j < 4; ++j) st4(B + (4 * tr + j) * LDSTR + 4 * tc, acc[j]);
  __syncthreads();               // A fully read, B fully written
  stage32(A, x, row0, M);
  __syncthreads();

  // ---- P2: pre2 = x@Wu1_top + aggr@Wu1_bot + bu1 ; h2 = relu(LN(pre2)) ----
  zero4(acc);
  gemm128(A, Wu1, tr, tc, acc);
  gemm128(B, Wu1 + 128 * HIDC, tr, tc, acc);
  {
    float4 b1 = ld4(bu1 + 4 * tc);
    float4 gv = ld4(gu  + 4 * tc);
    float4 bv = ld4(bun + 4 * tc);
#pragma unroll
    for (int j = 0; j < 4; ++j) {
      float4 v = acc[j];
      v.x += b1.x; v.y += b1.y; v.z += b1.z; v.w += b1.w;
      float s = v.x + v.y + v.z + v.w;
      float q = v.x * v.x + v.y * v.y + v.z * v.z + v.w * v.w;
#pragma unroll
      for (int m = 16; m >= 1; m >>= 1) { s += __shfl_xor(s, m); q += __shfl_xor(q, m); }
      float mu   = s * (1.0f / 128.0f);
      float var  = q * (1.0f / 128.0f) - mu * mu;
      float rstd = rsqrtf(var + 1e-5f);
      v.x = fmaxf(0.f, (v.x - mu) * rstd * gv.x + bv.x);
      v.y = fmaxf(0.f, (v.y - mu) * rstd * gv.y + bv.y);
      v.z = fmaxf(0.f, (v.z - mu) * rstd * gv.z + bv.z);
      v.w = fmaxf(0.f, (v.w - mu) * rstd * gv.w + bv.w);
      acc[j] = v;
    }
  }
  __syncthreads();               // all threads done reading B (aggr)
#pragma unroll
  for (int j = 0; j < 4; ++j) st4(B + (4 * tr + j) * LDSTR + 4 * tc, acc[j]);  // h2 -> B
  __syncthreads();

  // ---- P3: x_new = h2@Wu2 + bu2 ----
  zero4(acc);
  gemm128(B, Wu2, tr, tc, acc);
  {
    float4 b2 = ld4(bu2 + 4 * tc);
#pragma unroll
    for (int j = 0; j < 4; ++j) {
      acc[j].x += b2.x; acc[j].y += b2.y; acc[j].z += b2.z; acc[j].w += b2.w;
      int r = row0 + 4 * tr + j;
      if (r < M) st4(xout + (size_t)r * HIDC + 4 * tc, acc[j]);
    }
  }

  // ---- P4 (layers 0..2): PQ_next = x_new @ Wm1_next ----
  if (PQn != nullptr) {
#pragma unroll
    for (int j = 0; j < 4; ++j) st4(A + (4 * tr + j) * LDSTR + 4 * tc, acc[j]); // x_new -> A
    __syncthreads();
    float4 acc2[4];
    zero4(acc2);
    gemm128(A, Wm1n, tr, tc, acc2);
#pragma unroll
    for (int j = 0; j < 4; ++j) {
      int r = row0 + 4 * tr + j;
      if (r < M) st4(PQn + (size_t)r * 256 + 4 * tc, acc2[j]);
    }
    zero4(acc2);
    gemm128(A, Wm1n + 128 * HIDC, tr, tc, acc2);
#pragma unroll
    for (int j = 0; j < 4; ++j) {
      int r = row0 + 4 * tr + j;
      if (r < M) st4(PQn + (size_t)r * 256 + 128 + 4 * tc, acc2[j]);
    }
  }
}

// ---------------- launch ----------------

extern "C" void kernel_launch(void* const* d_in, const int* in_sizes, int n_in,
                              void* d_out, int out_size, void* d_ws, size_t ws_size,
                              hipStream_t stream)
{
  const float*  x_in = (const float*)d_in[0];
  const edge_t* ei   = (const edge_t*)d_in[1];
  const float*  Wm1  = (const float*)d_in[2];
  const float*  bm1  = (const float*)d_in[3];
  const float*  gm   = (const float*)d_in[4];
  const float*  bmn  = (const float*)d_in[5];
  const float*  Wm2  = (const float*)d_in[6];
  const float*  bm2  = (const float*)d_in[7];
  const float*  Wu1  = (const float*)d_in[8];
  const float*  bu1  = (const float*)d_in[9];
  const float*  gu   = (const float*)d_in[10];
  const float*  bun  = (const float*)d_in[11];
  const float*  Wu2  = (const float*)d_in[12];
  const float*  bu2  = (const float*)d_in[13];

  const int N = NNODES, E = NEDGES;

  char* ws = (char*)d_ws;
  float* PQ   = (float*)(ws + 0);            // N*256*4 = 51,200,000
  float* Hb   = (float*)(ws + 51200000);     // N*128*4 = 25,600,000
  int*   deg  = (int*)  (ws + 51200000);     // aliases Hb: used only during CSR build,
                                             // before the first agg_kernel writes H
  float* xA   = (float*)(ws + 76800000);     // 25,600,000
  float* xB   = (float*)(ws + 102400000);    // 25,600,000
  int* row_ptr  = (int*)(ws + 128000000);    // (N+1)*4
  int* fill_ptr = (int*)(ws + 128200064);    // N*4
  int* adj      = (int*)(ws + 128400064);    // E*4 = 2,000,000  (end: 130,400,064)

  const int gemmBlocks = (N + TM - 1) / TM;          // 1563
  const int aggBlocks  = (N + 3) / 4;                // 4 waves (nodes) per block

  // ---- CSR build (once per call, shared by all 4 layers) ----
  hipMemsetAsync(deg, 0, (size_t)N * 4, stream);
  count_kernel<<<(E + THREADS - 1) / THREADS, THREADS, 0, stream>>>(ei, deg, E);
  scan_kernel<<<1, 1024, 0, stream>>>(deg, row_ptr, fill_ptr, N);
  fill_kernel<<<(E + THREADS - 1) / THREADS, THREADS, 0, stream>>>(ei, fill_ptr, adj, E);

  // PQ for layer 0 from the input features
  pq_kernel<<<gemmBlocks, THREADS, 0, stream>>>(x_in, Wm1, PQ, N);

  const float* xc = x_in;
  float* xnext[4] = {xA, xB, xA, (float*)d_out};

  for (int l = 0; l < 4; ++l) {
    agg_kernel<<<aggBlocks, THREADS, 0, stream>>>(
        PQ, row_ptr, adj, bm1 + l * HIDC, gm + l * HIDC, bmn + l * HIDC, Hb, N);
    fused_update<<<gemmBlocks, THREADS, 0, stream>>>(
        xc, Hb, row_ptr,
        Wm2 + (size_t)l * HIDC * HIDC, bm2 + l * HIDC,
        Wu1 + (size_t)l * 256 * HIDC,  bu1 + l * HIDC,
        gu + l * HIDC, bun + l * HIDC,
        Wu2 + (size_t)l * HIDC * HIDC, bu2 + l * HIDC,
        xnext[l],
        (l < 3) ? (Wm1 + (size_t)(l + 1) * 256 * HIDC) : nullptr,
        (l < 3) ? PQ : nullptr,
        N);
    xc = xnext[l];
  }
}

// Round 10
// 906.282 us; speedup vs baseline: 2.9607x; 1.4268x over previous
//
#include <hip/hip_runtime.h>
#include <cstdint>
#include <cstddef>

// GraphWeather processor. R9/R10: fused_update -> MFMA (bf16 hi/lo split, 3 mfma/product).
//   R8 counters: fused_update 197us x4 = 61% of 1293us, MfmaUtil 0, VALUBusy 42%,
//   HBM 6.7% -> fp32-vector-GEMM bound. Node GEMMs moved to mfma_f32_16x16x32_bf16.
//   R10 fix: static __shared__ (67584 B) instead of dynamic LDS > 64KB (launch risk).
// Structure: CSR gather-aggregate (R6, verified: WRITE_SIZE 550MB->75MB) + factored
//   edge GEMMs (P=x@Wm1_top, Q=x@Wm1_bot; aggr=segsum(h)@Wm2+(indeg+1)*bm2).

#define THREADS 256
constexpr int HIDC   = 128;
constexpr int NNODES = 50000;
constexpr int NEDGES = 500000;
constexpr int TM     = 32;    // pq_kernel tile rows
constexpr int LDSTR  = 132;

typedef int edge_t;
typedef unsigned int uint32;
typedef __attribute__((ext_vector_type(8)))  short s8v;   // bf16x8 MFMA operand
typedef __attribute__((ext_vector_type(4)))  short s4vv;
typedef __attribute__((ext_vector_type(4)))  float f4v;   // MFMA accumulator

__device__ __forceinline__ float4 ld4(const float* p) { return *reinterpret_cast<const float4*>(p); }
__device__ __forceinline__ void  st4(float* p, float4 v) { *reinterpret_cast<float4*>(p) = v; }

// ---------------- fp32 helpers for pq_kernel (unchanged from R8) ----------------

__device__ __forceinline__ void stage32(float* dst, const float* __restrict__ src, int row0, int M)
{
  const int tid = threadIdx.x;
#pragma unroll
  for (int i = 0; i < 4; ++i) {
    int f  = i * THREADS + tid;
    int r  = f >> 5;
    int c4 = (f & 31) * 4;
    int gr = row0 + r; if (gr > M - 1) gr = M - 1;
    st4(dst + r * LDSTR + c4, ld4(src + (size_t)gr * HIDC + c4));
  }
}

__device__ __forceinline__ void gemm128(const float* A, const float* __restrict__ W,
                                        int tr, int tc, float4 acc[4])
{
  const float* a0 = A + (4 * tr + 0) * LDSTR;
  const float* a1 = A + (4 * tr + 1) * LDSTR;
  const float* a2 = A + (4 * tr + 2) * LDSTR;
  const float* a3 = A + (4 * tr + 3) * LDSTR;
  const float* wp = W + 4 * tc;
#pragma unroll 2
  for (int k = 0; k < 128; k += 4) {
    float4 va0 = ld4(a0 + k), va1 = ld4(a1 + k), va2 = ld4(a2 + k), va3 = ld4(a3 + k);
    float av[4][4] = {{va0.x, va0.y, va0.z, va0.w},
                      {va1.x, va1.y, va1.z, va1.w},
                      {va2.x, va2.y, va2.z, va2.w},
                      {va3.x, va3.y, va3.z, va3.w}};
#pragma unroll
    for (int kk = 0; kk < 4; ++kk) {
      float4 w = ld4(wp + (size_t)(k + kk) * HIDC);
#pragma unroll
      for (int j = 0; j < 4; ++j) {
        acc[j].x = fmaf(av[j][kk], w.x, acc[j].x);
        acc[j].y = fmaf(av[j][kk], w.y, acc[j].y);
        acc[j].z = fmaf(av[j][kk], w.z, acc[j].z);
        acc[j].w = fmaf(av[j][kk], w.w, acc[j].w);
      }
    }
  }
}

// ---------------- CSR build (unchanged, verified R8) ----------------

__global__ __launch_bounds__(THREADS) void count_kernel(const edge_t* __restrict__ ei,
                                                        int* __restrict__ deg, int E)
{
  int e = blockIdx.x * THREADS + threadIdx.x;
  if (e < E) atomicAdd(deg + ei[E + e], 1);
}

__global__ __launch_bounds__(1024) void scan_kernel(const int* __restrict__ deg,
                                                    int* __restrict__ row_ptr,
                                                    int* __restrict__ fill_ptr, int N)
{
  __shared__ int part[1024];
  const int t = threadIdx.x;
  const int chunk = (N + 1023) >> 10;
  const int beg = t * chunk;
  const int end = min(beg + chunk, N);
  int s = 0;
  for (int i = beg; i < end; ++i) s += deg[i];
  part[t] = s;
  __syncthreads();
  for (int off = 1; off < 1024; off <<= 1) {
    int v = (t >= off) ? part[t - off] : 0;
    __syncthreads();
    part[t] += v;
    __syncthreads();
  }
  int run = part[t] - s;
  for (int i = beg; i < end; ++i) {
    row_ptr[i] = run; fill_ptr[i] = run; run += deg[i];
  }
  if (t == 1023) row_ptr[N] = run;
}

__global__ __launch_bounds__(THREADS) void fill_kernel(const edge_t* __restrict__ ei,
                                                       int* __restrict__ fill_ptr,
                                                       int* __restrict__ adj, int E)
{
  int e = blockIdx.x * THREADS + threadIdx.x;
  if (e < E) {
    int s = (int)ei[e], d = (int)ei[E + e];
    int pos = atomicAdd(fill_ptr + d, 1);
    adj[pos] = s;
  }
}

// ---------------- W pre-pack: fp32 -> bf16 hi/lo in MFMA B-fragment order ----------------
// B-frag layout (16x16x32): col = lane&15, k = 32*ks + 8*(lane>>4) + j (j=0..7 contiguous).
// Per matrix m (128x128): byte layout = (ks*8+ct)*2048 + split*1024 + lane*16 (+2*j).
// Matrices: m = 0..3 Wm2[l]; 4..7 Wu1top[l]; 8..11 Wu1bot[l]; 12..15 Wu2[l];
//           16..19 Wm1top[l]; 20..23 Wm1bot[l].
__global__ __launch_bounds__(THREADS) void pack_w(const float* __restrict__ Wm1,
                                                  const float* __restrict__ Wm2,
                                                  const float* __restrict__ Wu1,
                                                  const float* __restrict__ Wu2,
                                                  unsigned short* __restrict__ Wp)
{
  int t = blockIdx.x * THREADS + threadIdx.x;
  if (t >= 24 * 16384) return;
  int m = t >> 14, e = t & 16383;
  int k = e >> 7, col = e & 127;
  const float* src;
  if      (m < 4)  src = Wm2 + (size_t)m        * 16384 +         k * 128 + col;
  else if (m < 8)  src = Wu1 + (size_t)(m - 4)  * 32768 +         k * 128 + col;
  else if (m < 12) src = Wu1 + (size_t)(m - 8)  * 32768 + 16384 + k * 128 + col;
  else if (m < 16) src = Wu2 + (size_t)(m - 12) * 16384 +         k * 128 + col;
  else if (m < 20) src = Wm1 + (size_t)(m - 16) * 32768 +         k * 128 + col;
  else             src = Wm1 + (size_t)(m - 20) * 32768 + 16384 + k * 128 + col;
  float w = *src;
  uint32 b = __float_as_uint(w);
  unsigned short hi = (unsigned short)(b >> 16);
  float fh = __uint_as_float(b & 0xFFFF0000u);
  unsigned short lo = (unsigned short)(__float_as_uint(w - fh) >> 16);
  int ks = k >> 5, kk = k & 31, g = kk >> 3, j = kk & 7;
  int lane = (g << 4) | (col & 15), ct = col >> 4;
  size_t base = (size_t)m * 32768 + (size_t)(ks * 8 + ct) * 1024 + (size_t)lane * 8 + j;
  Wp[base]       = hi;   // split 0 (hi)
  Wp[base + 512] = lo;   // split 1 (lo): +1024 bytes
}

// ---------------- pq_kernel (fp32, layer 0 only; unchanged) ----------------

__global__ __launch_bounds__(THREADS) void pq_kernel(const float* __restrict__ x,
                                                     const float* __restrict__ Wm1,
                                                     float* __restrict__ PQ, int M)
{
  __shared__ float A[TM * LDSTR];
  const int row0 = blockIdx.x * TM;
  stage32(A, x, row0, M);
  __syncthreads();
  const int tc = threadIdx.x & 31, tr = threadIdx.x >> 5;

  float4 acc[4];
#pragma unroll
  for (int j = 0; j < 4; ++j) acc[j] = make_float4(0.f, 0.f, 0.f, 0.f);
  gemm128(A, Wm1, tr, tc, acc);
#pragma unroll
  for (int j = 0; j < 4; ++j) {
    int r = row0 + 4 * tr + j;
    if (r < M) st4(PQ + (size_t)r * 256 + 4 * tc, acc[j]);
  }
#pragma unroll
  for (int j = 0; j < 4; ++j) acc[j] = make_float4(0.f, 0.f, 0.f, 0.f);
  gemm128(A, Wm1 + 128 * HIDC, tr, tc, acc);
#pragma unroll
  for (int j = 0; j < 4; ++j) {
    int r = row0 + 4 * tr + j;
    if (r < M) st4(PQ + (size_t)r * 256 + 128 + 4 * tc, acc[j]);
  }
}

// ---------------- agg_kernel (unchanged, verified R8) ----------------

__global__ __launch_bounds__(THREADS) void agg_kernel(const float* __restrict__ PQ,
                                                      const int* __restrict__ row_ptr,
                                                      const int* __restrict__ adj,
                                                      const float* __restrict__ bm1,
                                                      const float* __restrict__ g,
                                                      const float* __restrict__ b,
                                                      float* __restrict__ H, int N)
{
  const int d    = (blockIdx.x * THREADS + threadIdx.x) >> 6;
  const int lane = threadIdx.x & 63;
  if (d >= N) return;

  const float2 bb = reinterpret_cast<const float2*>(bm1)[lane];
  const float2 pv = *reinterpret_cast<const float2*>(PQ + (size_t)d * 256 + 2 * lane);
  const float bx = pv.x + bb.x, by = pv.y + bb.y;
  const float2 gg = reinterpret_cast<const float2*>(g)[lane];
  const float2 bl = reinterpret_cast<const float2*>(b)[lane];

  const int beg = row_ptr[d];
  const int cnt = row_ptr[d + 1] - beg;

  float2 q = *reinterpret_cast<const float2*>(PQ + (size_t)d * 256 + 128 + 2 * lane);
  float a0 = 0.f, a1 = 0.f;
  for (int i = 0; i <= cnt; ++i) {
    float2 qn = make_float2(0.f, 0.f);
    if (i < cnt) {
      int s = adj[beg + i];
      qn = *reinterpret_cast<const float2*>(PQ + (size_t)s * 256 + 128 + 2 * lane);
    }
    float x0 = bx + q.x, x1 = by + q.y;
    float sum = x0 + x1, sq = x0 * x0 + x1 * x1;
#pragma unroll
    for (int m = 32; m >= 1; m >>= 1) { sum += __shfl_xor(sum, m); sq += __shfl_xor(sq, m); }
    float mu   = sum * (1.0f / 128.0f);
    float var  = sq * (1.0f / 128.0f) - mu * mu;
    float rstd = rsqrtf(var + 1e-5f);
    a0 += fmaxf(0.f, (x0 - mu) * rstd * gg.x + bl.x);
    a1 += fmaxf(0.f, (x1 - mu) * rstd * gg.y + bl.y);
    q = qn;
  }
  *reinterpret_cast<float2*>(H + (size_t)d * HIDC + 2 * lane) = make_float2(a0, a1);
}

// ---------------- MFMA fused update ----------------
// Block: 64 rows, 256 thr = 4 waves. Wave w: 4 row-tiles x 2 col-tiles (cols 32w..32w+31).
// LDS (static, 67584 B): Abuf hi/lo (64x128 bf16 each, XOR-swizzled), Bbuf hi/lo, LN partials.
// Frag layouts: A row=lane&15, k=8*(lane>>4)+j; B col=lane&15, same k; C/D col=lane&15,
// row=4*(lane>>4)+reg [m89]. Split: acc += Ah*Wh + Al*Wh + Ah*Wl.

__device__ __forceinline__ void stage_bf(char* lds, int hiOff,
                                         const float* __restrict__ src, int row0, int M)
{
  const int t = threadIdx.x;
#pragma unroll
  for (int i = 0; i < 8; ++i) {
    int f = i * THREADS + t;           // 2048 float4 slots = 64 rows x 32
    int r = f >> 5, c4 = (f & 31) * 4;
    int gr = row0 + r; if (gr > M - 1) gr = M - 1;
    float4 v = ld4(src + (size_t)gr * HIDC + c4);
    float vv[4] = {v.x, v.y, v.z, v.w};
    short h[4], l[4];
#pragma unroll
    for (int j = 0; j < 4; ++j) {
      uint32 b = __float_as_uint(vv[j]);
      h[j] = (short)(b >> 16);
      float fh = __uint_as_float(b & 0xFFFF0000u);
      l[j] = (short)(__float_as_uint(vv[j] - fh) >> 16);
    }
    int off = r * 256 + ((c4 * 2) ^ ((r & 7) << 4));
    s4vv hv = {h[0], h[1], h[2], h[3]};
    s4vv lv = {l[0], l[1], l[2], l[3]};
    *reinterpret_cast<s4vv*>(lds + hiOff + off) = hv;
    *reinterpret_cast<s4vv*>(lds + hiOff + 16384 + off) = lv;
  }
}

__device__ __forceinline__ void put_bf(char* lds, int hiOff, int r, int colb, float v)
{
  uint32 b = __float_as_uint(v);
  short hh = (short)(b >> 16);
  float fh = __uint_as_float(b & 0xFFFF0000u);
  short ll = (short)(__float_as_uint(v - fh) >> 16);
  int off = r * 256 + (colb ^ ((r & 7) << 4));
  *reinterpret_cast<short*>(lds + hiOff + off) = hh;
  *reinterpret_cast<short*>(lds + hiOff + 16384 + off) = ll;
}

__device__ __forceinline__ void gemm_bf(const char* lds, int hiOff,
                                        const char* __restrict__ wp,
                                        int w, int lane, f4v acc[4][2])
{
  const int lol = lane & 15, g = lane >> 4, sw = (lane & 7) << 4;
#pragma unroll
  for (int ks = 0; ks < 4; ++ks) {
    const int cb = (64 * ks + 16 * g) ^ sw;
    s8v ah[4], al[4];
#pragma unroll
    for (int rt = 0; rt < 4; ++rt) {
      int rb = (16 * rt + lol) * 256;
      ah[rt] = *reinterpret_cast<const s8v*>(lds + hiOff + rb + cb);
      al[rt] = *reinterpret_cast<const s8v*>(lds + hiOff + 16384 + rb + cb);
    }
#pragma unroll
    for (int cp = 0; cp < 2; ++cp) {
      const char* base = wp + (size_t)(ks * 8 + 2 * w + cp) * 2048 + (size_t)lane * 16;
      s8v wh = *reinterpret_cast<const s8v*>(base);
      s8v wl = *reinterpret_cast<const s8v*>(base + 1024);
#pragma unroll
      for (int rt = 0; rt < 4; ++rt) {
        acc[rt][cp] = __builtin_amdgcn_mfma_f32_16x16x32_bf16(ah[rt], wh, acc[rt][cp], 0, 0, 0);
        acc[rt][cp] = __builtin_amdgcn_mfma_f32_16x16x32_bf16(al[rt], wh, acc[rt][cp], 0, 0, 0);
        acc[rt][cp] = __builtin_amdgcn_mfma_f32_16x16x32_bf16(ah[rt], wl, acc[rt][cp], 0, 0, 0);
      }
    }
  }
}

__device__ __forceinline__ void zero_acc(f4v acc[4][2])
{
#pragma unroll
  for (int rt = 0; rt < 4; ++rt)
#pragma unroll
    for (int cp = 0; cp < 2; ++cp)
      acc[rt][cp] = (f4v){0.f, 0.f, 0.f, 0.f};
}

__global__ __launch_bounds__(THREADS) void fused_mfma(
    const float* __restrict__ x, const float* __restrict__ Hin,
    const int* __restrict__ rp, const char* __restrict__ Wp, int layer,
    const float* __restrict__ bm2, const float* __restrict__ bu1,
    const float* __restrict__ gu,  const float* __restrict__ bun,
    const float* __restrict__ bu2,
    float* __restrict__ xout, float* __restrict__ PQn, int M)
{
  __shared__ char lds[67584];          // static: 2x 32KB bf16 hi/lo bufs + 2KB LN partials
  const int AH = 0, BH = 32768, PART = 65536;
  const int t = threadIdx.x, w = t >> 6, lane = t & 63;
  const int g = lane >> 4, lol = lane & 15;
  const int row0 = blockIdx.x * 64;
  const int colL0 = 32 * w + lol, colL1 = colL0 + 16;

  f4v acc[4][2];

  // ---- P1: aggr = H@Wm2 + (indeg+1)*bm2 -> Bbuf ----
  stage_bf(lds, AH, Hin, row0, M);
  __syncthreads();
  zero_acc(acc);
  gemm_bf(lds, AH, Wp + (size_t)(0 + layer) * 65536, w, lane, acc);
  {
    float b0 = bm2[colL0], b1 = bm2[colL1];
#pragma unroll
    for (int rt = 0; rt < 4; ++rt)
#pragma unroll
      for (int reg = 0; reg < 4; ++reg) {
        int r  = 16 * rt + 4 * g + reg;
        int rg = row0 + r; if (rg > M - 1) rg = M - 1;
        float c = (float)(rp[rg + 1] - rp[rg]) + 1.0f;
        put_bf(lds, BH, r, 2 * colL0, acc[rt][0][reg] + c * b0);
        put_bf(lds, BH, r, 2 * colL1, acc[rt][1][reg] + c * b1);
      }
  }
  __syncthreads();
  stage_bf(lds, AH, x, row0, M);
  __syncthreads();

  // ---- P2: pre2 = x@Wu1top + aggr@Wu1bot + bu1; h2 = relu(LN(pre2)) -> Bbuf ----
  zero_acc(acc);
  gemm_bf(lds, AH, Wp + (size_t)(4 + layer) * 65536, w, lane, acc);
  gemm_bf(lds, BH, Wp + (size_t)(8 + layer) * 65536, w, lane, acc);
  {
    float b0 = bu1[colL0], b1 = bu1[colL1];
#pragma unroll
    for (int rt = 0; rt < 4; ++rt)
#pragma unroll
      for (int reg = 0; reg < 4; ++reg) {
        acc[rt][0][reg] += b0;
        acc[rt][1][reg] += b1;
        float s = acc[rt][0][reg] + acc[rt][1][reg];
        float q = acc[rt][0][reg] * acc[rt][0][reg] + acc[rt][1][reg] * acc[rt][1][reg];
#pragma unroll
        for (int m = 8; m >= 1; m >>= 1) { s += __shfl_xor(s, m); q += __shfl_xor(q, m); }
        if (lol == 0) {
          int r = 16 * rt + 4 * g + reg;
          *reinterpret_cast<float2*>(lds + PART + (r * 4 + w) * 8) = make_float2(s, q);
        }
      }
  }
  __syncthreads();
  {
    float g0 = gu[colL0],  g1 = gu[colL1];
    float n0 = bun[colL0], n1 = bun[colL1];
#pragma unroll
    for (int rt = 0; rt < 4; ++rt)
#pragma unroll
      for (int reg = 0; reg < 4; ++reg) {
        int r = 16 * rt + 4 * g + reg;
        float S = 0.f, Q = 0.f;
#pragma unroll
        for (int wv = 0; wv < 4; ++wv) {
          float2 p = *reinterpret_cast<const float2*>(lds + PART + (r * 4 + wv) * 8);
          S += p.x; Q += p.y;
        }
        float mu   = S * (1.0f / 128.0f);
        float var  = Q * (1.0f / 128.0f) - mu * mu;
        float rstd = rsqrtf(var + 1e-5f);
        float v0 = fmaxf(0.f, (acc[rt][0][reg] - mu) * rstd * g0 + n0);
        float v1 = fmaxf(0.f, (acc[rt][1][reg] - mu) * rstd * g1 + n1);
        put_bf(lds, BH, r, 2 * colL0, v0);
        put_bf(lds, BH, r, 2 * colL1, v1);
      }
  }
  __syncthreads();

  // ---- P3: x_new = h2@Wu2 + bu2 -> global (+ Abuf for P4) ----
  zero_acc(acc);
  gemm_bf(lds, BH, Wp + (size_t)(12 + layer) * 65536, w, lane, acc);
  {
    float b0 = bu2[colL0], b1 = bu2[colL1];
#pragma unroll
    for (int rt = 0; rt < 4; ++rt)
#pragma unroll
      for (int reg = 0; reg < 4; ++reg) {
        int r  = 16 * rt + 4 * g + reg;
        int rg = row0 + r;
        float v0 = acc[rt][0][reg] + b0;
        float v1 = acc[rt][1][reg] + b1;
        if (rg < M) {
          xout[(size_t)rg * HIDC + colL0] = v0;
          xout[(size_t)rg * HIDC + colL1] = v1;
        }
        if (PQn != nullptr) {
          put_bf(lds, AH, r, 2 * colL0, v0);
          put_bf(lds, AH, r, 2 * colL1, v1);
        }
      }
  }

  // ---- P4 (layers 0..2): PQ_next = x_new @ Wm1_{l+1} ----
  if (PQn != nullptr) {
    __syncthreads();
    zero_acc(acc);
    gemm_bf(lds, AH, Wp + (size_t)(17 + layer) * 65536, w, lane, acc);   // Wm1top[l+1]
#pragma unroll
    for (int rt = 0; rt < 4; ++rt)
#pragma unroll
      for (int reg = 0; reg < 4; ++reg) {
        int rg = row0 + 16 * rt + 4 * g + reg;
        if (rg < M) {
          PQn[(size_t)rg * 256 + colL0] = acc[rt][0][reg];
          PQn[(size_t)rg * 256 + colL1] = acc[rt][1][reg];
        }
      }
    zero_acc(acc);
    gemm_bf(lds, AH, Wp + (size_t)(21 + layer) * 65536, w, lane, acc);   // Wm1bot[l+1]
#pragma unroll
    for (int rt = 0; rt < 4; ++rt)
#pragma unroll
      for (int reg = 0; reg < 4; ++reg) {
        int rg = row0 + 16 * rt + 4 * g + reg;
        if (rg < M) {
          PQn[(size_t)rg * 256 + 128 + colL0] = acc[rt][0][reg];
          PQn[(size_t)rg * 256 + 128 + colL1] = acc[rt][1][reg];
        }
      }
  }
}

// ---------------- launch ----------------

extern "C" void kernel_launch(void* const* d_in, const int* in_sizes, int n_in,
                              void* d_out, int out_size, void* d_ws, size_t ws_size,
                              hipStream_t stream)
{
  const float*  x_in = (const float*)d_in[0];
  const edge_t* ei   = (const edge_t*)d_in[1];
  const float*  Wm1  = (const float*)d_in[2];
  const float*  bm1  = (const float*)d_in[3];
  const float*  gm   = (const float*)d_in[4];
  const float*  bmn  = (const float*)d_in[5];
  const float*  Wm2  = (const float*)d_in[6];
  const float*  bm2  = (const float*)d_in[7];
  const float*  Wu1  = (const float*)d_in[8];
  const float*  bu1  = (const float*)d_in[9];
  const float*  gu   = (const float*)d_in[10];
  const float*  bun  = (const float*)d_in[11];
  const float*  Wu2  = (const float*)d_in[12];
  const float*  bu2  = (const float*)d_in[13];

  const int N = NNODES, E = NEDGES;

  char* ws = (char*)d_ws;
  float* PQ   = (float*)(ws + 0);            // 51,200,000
  float* Hb   = (float*)(ws + 51200000);     // 25,600,000 (aliases deg during CSR build)
  int*   deg  = (int*)  (ws + 51200000);
  float* xA   = (float*)(ws + 76800000);     // 25,600,000
  float* xB   = (float*)(ws + 102400000);    // 25,600,000
  int* row_ptr  = (int*)(ws + 128000000);    // (N+1)*4
  int* fill_ptr = (int*)(ws + 128200064);    // N*4
  int* adj      = (int*)(ws + 128400064);    // E*4 = 2,000,000
  char* Wp      = ws + 130400064;            // 24 * 65536 = 1,572,864 (end ~132.0 MB)

  const int pqBlocks   = (N + TM - 1) / TM;          // 1563
  const int aggBlocks  = (N + 3) / 4;
  const int fusBlocks  = (N + 63) / 64;              // 782

  // CSR build + weight pre-pack (once per call)
  hipMemsetAsync(deg, 0, (size_t)N * 4, stream);
  count_kernel<<<(E + THREADS - 1) / THREADS, THREADS, 0, stream>>>(ei, deg, E);
  scan_kernel<<<1, 1024, 0, stream>>>(deg, row_ptr, fill_ptr, N);
  fill_kernel<<<(E + THREADS - 1) / THREADS, THREADS, 0, stream>>>(ei, fill_ptr, adj, E);
  pack_w<<<(24 * 16384 + THREADS - 1) / THREADS, THREADS, 0, stream>>>(
      Wm1, Wm2, Wu1, Wu2, (unsigned short*)Wp);

  pq_kernel<<<pqBlocks, THREADS, 0, stream>>>(x_in, Wm1, PQ, N);

  const float* xc = x_in;
  float* xnext[4] = {xA, xB, xA, (float*)d_out};

  for (int l = 0; l < 4; ++l) {
    agg_kernel<<<aggBlocks, THREADS, 0, stream>>>(
        PQ, row_ptr, adj, bm1 + l * HIDC, gm + l * HIDC, bmn + l * HIDC, Hb, N);
    fused_mfma<<<fusBlocks, THREADS, 0, stream>>>(
        xc, Hb, row_ptr, Wp, l,
        bm2 + l * HIDC, bu1 + l * HIDC, gu + l * HIDC, bun + l * HIDC, bu2 + l * HIDC,
        xnext[l], (l < 3) ? PQ : nullptr, N);
    xc = xnext[l];
  }
}

// Round 11
// 806.583 us; speedup vs baseline: 3.3267x; 1.1236x over previous
//
#include <hip/hip_runtime.h>
#include <cstdint>
#include <cstddef>

// GraphWeather processor. R11: parallel 3-kernel CSR scan (R10's single-block scan
//   was top dispatch: 110us on 1 CU, 0.06% HBM -> serial-latency bound).
// R10: fused_update -> MFMA bf16 hi/lo split (verified: 1293 -> 906 us, absmax same).
// R6: CSR gather-aggregate (verified: WRITE_SIZE 550MB -> 75MB).
// Factored GEMMs: P=x@Wm1_top, Q=x@Wm1_bot; aggr=segsum(h)@Wm2+(indeg+1)*bm2.

#define THREADS 256
constexpr int HIDC   = 128;
constexpr int NNODES = 50000;
constexpr int NEDGES = 500000;
constexpr int TM     = 32;    // pq_kernel tile rows
constexpr int LDSTR  = 132;
constexpr int SCAN_B = 256;                            // scan blocks
constexpr int CHUNK  = (NNODES + SCAN_B - 1) / SCAN_B; // 196 elements/block

typedef int edge_t;
typedef unsigned int uint32;
typedef __attribute__((ext_vector_type(8)))  short s8v;   // bf16x8 MFMA operand
typedef __attribute__((ext_vector_type(4)))  short s4vv;
typedef __attribute__((ext_vector_type(4)))  float f4v;   // MFMA accumulator

__device__ __forceinline__ float4 ld4(const float* p) { return *reinterpret_cast<const float4*>(p); }
__device__ __forceinline__ void  st4(float* p, float4 v) { *reinterpret_cast<float4*>(p) = v; }

// ---------------- fp32 helpers for pq_kernel ----------------

__device__ __forceinline__ void stage32(float* dst, const float* __restrict__ src, int row0, int M)
{
  const int tid = threadIdx.x;
#pragma unroll
  for (int i = 0; i < 4; ++i) {
    int f  = i * THREADS + tid;
    int r  = f >> 5;
    int c4 = (f & 31) * 4;
    int gr = row0 + r; if (gr > M - 1) gr = M - 1;
    st4(dst + r * LDSTR + c4, ld4(src + (size_t)gr * HIDC + c4));
  }
}

__device__ __forceinline__ void gemm128(const float* A, const float* __restrict__ W,
                                        int tr, int tc, float4 acc[4])
{
  const float* a0 = A + (4 * tr + 0) * LDSTR;
  const float* a1 = A + (4 * tr + 1) * LDSTR;
  const float* a2 = A + (4 * tr + 2) * LDSTR;
  const float* a3 = A + (4 * tr + 3) * LDSTR;
  const float* wp = W + 4 * tc;
#pragma unroll 2
  for (int k = 0; k < 128; k += 4) {
    float4 va0 = ld4(a0 + k), va1 = ld4(a1 + k), va2 = ld4(a2 + k), va3 = ld4(a3 + k);
    float av[4][4] = {{va0.x, va0.y, va0.z, va0.w},
                      {va1.x, va1.y, va1.z, va1.w},
                      {va2.x, va2.y, va2.z, va2.w},
                      {va3.x, va3.y, va3.z, va3.w}};
#pragma unroll
    for (int kk = 0; kk < 4; ++kk) {
      float4 w = ld4(wp + (size_t)(k + kk) * HIDC);
#pragma unroll
      for (int j = 0; j < 4; ++j) {
        acc[j].x = fmaf(av[j][kk], w.x, acc[j].x);
        acc[j].y = fmaf(av[j][kk], w.y, acc[j].y);
        acc[j].z = fmaf(av[j][kk], w.z, acc[j].z);
        acc[j].w = fmaf(av[j][kk], w.w, acc[j].w);
      }
    }
  }
}

// ---------------- CSR build ----------------

__global__ __launch_bounds__(THREADS) void count_kernel(const edge_t* __restrict__ ei,
                                                        int* __restrict__ deg, int E)
{
  int e = blockIdx.x * THREADS + threadIdx.x;
  if (e < E) atomicAdd(deg + ei[E + e], 1);
}

// scan stage 1: per-block chunk sums (256 blocks x 196 elems)
__global__ __launch_bounds__(THREADS) void scan_part(const int* __restrict__ deg,
                                                     int* __restrict__ bsum, int N)
{
  const int b = blockIdx.x, t = threadIdx.x;
  const int i = b * CHUNK + t;
  int v = (t < CHUNK && i < N) ? deg[i] : 0;
#pragma unroll
  for (int m = 32; m >= 1; m >>= 1) v += __shfl_xor(v, m);
  __shared__ int wsum[4];
  if ((t & 63) == 0) wsum[t >> 6] = v;
  __syncthreads();
  if (t == 0) bsum[b] = wsum[0] + wsum[1] + wsum[2] + wsum[3];
}

// scan stage 2: exclusive scan of 256 block sums (1 tiny block)
__global__ __launch_bounds__(SCAN_B) void scan_top(const int* __restrict__ bsum,
                                                   int* __restrict__ boff)
{
  __shared__ int s[SCAN_B];
  const int t = threadIdx.x;
  int v = bsum[t];
  s[t] = v;
  __syncthreads();
  for (int off = 1; off < SCAN_B; off <<= 1) {
    int u = (t >= off) ? s[t - off] : 0;
    __syncthreads();
    s[t] += u;
    __syncthreads();
  }
  boff[t] = s[t] - v;   // exclusive prefix of block sums
}

// scan stage 3: in-block scan + block offset -> row_ptr / fill_ptr
__global__ __launch_bounds__(THREADS) void scan_write(const int* __restrict__ deg,
                                                      const int* __restrict__ boff,
                                                      int* __restrict__ row_ptr,
                                                      int* __restrict__ fill_ptr, int N, int E)
{
  __shared__ int s[THREADS];
  const int b = blockIdx.x, t = threadIdx.x;
  const int i = b * CHUNK + t;
  const bool ok = (t < CHUNK && i < N);
  int v = ok ? deg[i] : 0;
  s[t] = v;
  __syncthreads();
  for (int off = 1; off < THREADS; off <<= 1) {
    int u = (t >= off) ? s[t - off] : 0;
    __syncthreads();
    s[t] += u;
    __syncthreads();
  }
  int excl = s[t] - v + boff[b];
  if (ok) {
    row_ptr[i] = excl;
    fill_ptr[i] = excl;
    if (i == N - 1) row_ptr[N] = E;
  }
}

__global__ __launch_bounds__(THREADS) void fill_kernel(const edge_t* __restrict__ ei,
                                                       int* __restrict__ fill_ptr,
                                                       int* __restrict__ adj, int E)
{
  int e = blockIdx.x * THREADS + threadIdx.x;
  if (e < E) {
    int s = (int)ei[e], d = (int)ei[E + e];
    int pos = atomicAdd(fill_ptr + d, 1);
    adj[pos] = s;
  }
}

// ---------------- W pre-pack: fp32 -> bf16 hi/lo in MFMA B-fragment order ----------------
// B-frag layout (16x16x32): col = lane&15, k = 32*ks + 8*(lane>>4) + j (j=0..7 contiguous).
// Per matrix m (128x128): byte layout = (ks*8+ct)*2048 + split*1024 + lane*16 (+2*j).
// Matrices: m = 0..3 Wm2[l]; 4..7 Wu1top[l]; 8..11 Wu1bot[l]; 12..15 Wu2[l];
//           16..19 Wm1top[l]; 20..23 Wm1bot[l].
__global__ __launch_bounds__(THREADS) void pack_w(const float* __restrict__ Wm1,
                                                  const float* __restrict__ Wm2,
                                                  const float* __restrict__ Wu1,
                                                  const float* __restrict__ Wu2,
                                                  unsigned short* __restrict__ Wp)
{
  int t = blockIdx.x * THREADS + threadIdx.x;
  if (t >= 24 * 16384) return;
  int m = t >> 14, e = t & 16383;
  int k = e >> 7, col = e & 127;
  const float* src;
  if      (m < 4)  src = Wm2 + (size_t)m        * 16384 +         k * 128 + col;
  else if (m < 8)  src = Wu1 + (size_t)(m - 4)  * 32768 +         k * 128 + col;
  else if (m < 12) src = Wu1 + (size_t)(m - 8)  * 32768 + 16384 + k * 128 + col;
  else if (m < 16) src = Wu2 + (size_t)(m - 12) * 16384 +         k * 128 + col;
  else if (m < 20) src = Wm1 + (size_t)(m - 16) * 32768 +         k * 128 + col;
  else             src = Wm1 + (size_t)(m - 20) * 32768 + 16384 + k * 128 + col;
  float w = *src;
  uint32 b = __float_as_uint(w);
  unsigned short hi = (unsigned short)(b >> 16);
  float fh = __uint_as_float(b & 0xFFFF0000u);
  unsigned short lo = (unsigned short)(__float_as_uint(w - fh) >> 16);
  int ks = k >> 5, kk = k & 31, g = kk >> 3, j = kk & 7;
  int lane = (g << 4) | (col & 15), ct = col >> 4;
  size_t base = (size_t)m * 32768 + (size_t)(ks * 8 + ct) * 1024 + (size_t)lane * 8 + j;
  Wp[base]       = hi;   // split 0 (hi)
  Wp[base + 512] = lo;   // split 1 (lo): +1024 bytes
}

// ---------------- pq_kernel (fp32, layer 0 only) ----------------

__global__ __launch_bounds__(THREADS) void pq_kernel(const float* __restrict__ x,
                                                     const float* __restrict__ Wm1,
                                                     float* __restrict__ PQ, int M)
{
  __shared__ float A[TM * LDSTR];
  const int row0 = blockIdx.x * TM;
  stage32(A, x, row0, M);
  __syncthreads();
  const int tc = threadIdx.x & 31, tr = threadIdx.x >> 5;

  float4 acc[4];
#pragma unroll
  for (int j = 0; j < 4; ++j) acc[j] = make_float4(0.f, 0.f, 0.f, 0.f);
  gemm128(A, Wm1, tr, tc, acc);
#pragma unroll
  for (int j = 0; j < 4; ++j) {
    int r = row0 + 4 * tr + j;
    if (r < M) st4(PQ + (size_t)r * 256 + 4 * tc, acc[j]);
  }
#pragma unroll
  for (int j = 0; j < 4; ++j) acc[j] = make_float4(0.f, 0.f, 0.f, 0.f);
  gemm128(A, Wm1 + 128 * HIDC, tr, tc, acc);
#pragma unroll
  for (int j = 0; j < 4; ++j) {
    int r = row0 + 4 * tr + j;
    if (r < M) st4(PQ + (size_t)r * 256 + 128 + 4 * tc, acc[j]);
  }
}

// ---------------- agg_kernel (unchanged, verified R8) ----------------

__global__ __launch_bounds__(THREADS) void agg_kernel(const float* __restrict__ PQ,
                                                      const int* __restrict__ row_ptr,
                                                      const int* __restrict__ adj,
                                                      const float* __restrict__ bm1,
                                                      const float* __restrict__ g,
                                                      const float* __restrict__ b,
                                                      float* __restrict__ H, int N)
{
  const int d    = (blockIdx.x * THREADS + threadIdx.x) >> 6;
  const int lane = threadIdx.x & 63;
  if (d >= N) return;

  const float2 bb = reinterpret_cast<const float2*>(bm1)[lane];
  const float2 pv = *reinterpret_cast<const float2*>(PQ + (size_t)d * 256 + 2 * lane);
  const float bx = pv.x + bb.x, by = pv.y + bb.y;
  const float2 gg = reinterpret_cast<const float2*>(g)[lane];
  const float2 bl = reinterpret_cast<const float2*>(b)[lane];

  const int beg = row_ptr[d];
  const int cnt = row_ptr[d + 1] - beg;

  float2 q = *reinterpret_cast<const float2*>(PQ + (size_t)d * 256 + 128 + 2 * lane);
  float a0 = 0.f, a1 = 0.f;
  for (int i = 0; i <= cnt; ++i) {
    float2 qn = make_float2(0.f, 0.f);
    if (i < cnt) {
      int s = adj[beg + i];
      qn = *reinterpret_cast<const float2*>(PQ + (size_t)s * 256 + 128 + 2 * lane);
    }
    float x0 = bx + q.x, x1 = by + q.y;
    float sum = x0 + x1, sq = x0 * x0 + x1 * x1;
#pragma unroll
    for (int m = 32; m >= 1; m >>= 1) { sum += __shfl_xor(sum, m); sq += __shfl_xor(sq, m); }
    float mu   = sum * (1.0f / 128.0f);
    float var  = sq * (1.0f / 128.0f) - mu * mu;
    float rstd = rsqrtf(var + 1e-5f);
    a0 += fmaxf(0.f, (x0 - mu) * rstd * gg.x + bl.x);
    a1 += fmaxf(0.f, (x1 - mu) * rstd * gg.y + bl.y);
    q = qn;
  }
  *reinterpret_cast<float2*>(H + (size_t)d * HIDC + 2 * lane) = make_float2(a0, a1);
}

// ---------------- MFMA fused update (verified R10: 197 -> <110 us/layer) ----------------
// Block: 64 rows, 256 thr = 4 waves. Wave w: 4 row-tiles x 2 col-tiles (cols 32w..32w+31).
// LDS (static, 67584 B): Abuf hi/lo (64x128 bf16 each, XOR-swizzled), Bbuf hi/lo, LN partials.
// Frag layouts: A row=lane&15, k=8*(lane>>4)+j; B col=lane&15, same k; C/D col=lane&15,
// row=4*(lane>>4)+reg. Split: acc += Ah*Wh + Al*Wh + Ah*Wl.

__device__ __forceinline__ void stage_bf(char* lds, int hiOff,
                                         const float* __restrict__ src, int row0, int M)
{
  const int t = threadIdx.x;
#pragma unroll
  for (int i = 0; i < 8; ++i) {
    int f = i * THREADS + t;           // 2048 float4 slots = 64 rows x 32
    int r = f >> 5, c4 = (f & 31) * 4;
    int gr = row0 + r; if (gr > M - 1) gr = M - 1;
    float4 v = ld4(src + (size_t)gr * HIDC + c4);
    float vv[4] = {v.x, v.y, v.z, v.w};
    short h[4], l[4];
#pragma unroll
    for (int j = 0; j < 4; ++j) {
      uint32 b = __float_as_uint(vv[j]);
      h[j] = (short)(b >> 16);
      float fh = __uint_as_float(b & 0xFFFF0000u);
      l[j] = (short)(__float_as_uint(vv[j] - fh) >> 16);
    }
    int off = r * 256 + ((c4 * 2) ^ ((r & 7) << 4));
    s4vv hv = {h[0], h[1], h[2], h[3]};
    s4vv lv = {l[0], l[1], l[2], l[3]};
    *reinterpret_cast<s4vv*>(lds + hiOff + off) = hv;
    *reinterpret_cast<s4vv*>(lds + hiOff + 16384 + off) = lv;
  }
}

__device__ __forceinline__ void put_bf(char* lds, int hiOff, int r, int colb, float v)
{
  uint32 b = __float_as_uint(v);
  short hh = (short)(b >> 16);
  float fh = __uint_as_float(b & 0xFFFF0000u);
  short ll = (short)(__float_as_uint(v - fh) >> 16);
  int off = r * 256 + (colb ^ ((r & 7) << 4));
  *reinterpret_cast<short*>(lds + hiOff + off) = hh;
  *reinterpret_cast<short*>(lds + hiOff + 16384 + off) = ll;
}

__device__ __forceinline__ void gemm_bf(const char* lds, int hiOff,
                                        const char* __restrict__ wp,
                                        int w, int lane, f4v acc[4][2])
{
  const int lol = lane & 15, g = lane >> 4, sw = (lane & 7) << 4;
#pragma unroll
  for (int ks = 0; ks < 4; ++ks) {
    const int cb = (64 * ks + 16 * g) ^ sw;
    s8v ah[4], al[4];
#pragma unroll
    for (int rt = 0; rt < 4; ++rt) {
      int rb = (16 * rt + lol) * 256;
      ah[rt] = *reinterpret_cast<const s8v*>(lds + hiOff + rb + cb);
      al[rt] = *reinterpret_cast<const s8v*>(lds + hiOff + 16384 + rb + cb);
    }
#pragma unroll
    for (int cp = 0; cp < 2; ++cp) {
      const char* base = wp + (size_t)(ks * 8 + 2 * w + cp) * 2048 + (size_t)lane * 16;
      s8v wh = *reinterpret_cast<const s8v*>(base);
      s8v wl = *reinterpret_cast<const s8v*>(base + 1024);
#pragma unroll
      for (int rt = 0; rt < 4; ++rt) {
        acc[rt][cp] = __builtin_amdgcn_mfma_f32_16x16x32_bf16(ah[rt], wh, acc[rt][cp], 0, 0, 0);
        acc[rt][cp] = __builtin_amdgcn_mfma_f32_16x16x32_bf16(al[rt], wh, acc[rt][cp], 0, 0, 0);
        acc[rt][cp] = __builtin_amdgcn_mfma_f32_16x16x32_bf16(ah[rt], wl, acc[rt][cp], 0, 0, 0);
      }
    }
  }
}

__device__ __forceinline__ void zero_acc(f4v acc[4][2])
{
#pragma unroll
  for (int rt = 0; rt < 4; ++rt)
#pragma unroll
    for (int cp = 0; cp < 2; ++cp)
      acc[rt][cp] = (f4v){0.f, 0.f, 0.f, 0.f};
}

__global__ __launch_bounds__(THREADS) void fused_mfma(
    const float* __restrict__ x, const float* __restrict__ Hin,
    const int* __restrict__ rp, const char* __restrict__ Wp, int layer,
    const float* __restrict__ bm2, const float* __restrict__ bu1,
    const float* __restrict__ gu,  const float* __restrict__ bun,
    const float* __restrict__ bu2,
    float* __restrict__ xout, float* __restrict__ PQn, int M)
{
  __shared__ char lds[67584];          // static: 2x 32KB bf16 hi/lo bufs + 2KB LN partials
  const int AH = 0, BH = 32768, PART = 65536;
  const int t = threadIdx.x, w = t >> 6, lane = t & 63;
  const int g = lane >> 4, lol = lane & 15;
  const int row0 = blockIdx.x * 64;
  const int colL0 = 32 * w + lol, colL1 = colL0 + 16;

  f4v acc[4][2];

  // ---- P1: aggr = H@Wm2 + (indeg+1)*bm2 -> Bbuf ----
  stage_bf(lds, AH, Hin, row0, M);
  __syncthreads();
  zero_acc(acc);
  gemm_bf(lds, AH, Wp + (size_t)(0 + layer) * 65536, w, lane, acc);
  {
    float b0 = bm2[colL0], b1 = bm2[colL1];
#pragma unroll
    for (int rt = 0; rt < 4; ++rt)
#pragma unroll
      for (int reg = 0; reg < 4; ++reg) {
        int r  = 16 * rt + 4 * g + reg;
        int rg = row0 + r; if (rg > M - 1) rg = M - 1;
        float c = (float)(rp[rg + 1] - rp[rg]) + 1.0f;
        put_bf(lds, BH, r, 2 * colL0, acc[rt][0][reg] + c * b0);
        put_bf(lds, BH, r, 2 * colL1, acc[rt][1][reg] + c * b1);
      }
  }
  __syncthreads();
  stage_bf(lds, AH, x, row0, M);
  __syncthreads();

  // ---- P2: pre2 = x@Wu1top + aggr@Wu1bot + bu1; h2 = relu(LN(pre2)) -> Bbuf ----
  zero_acc(acc);
  gemm_bf(lds, AH, Wp + (size_t)(4 + layer) * 65536, w, lane, acc);
  gemm_bf(lds, BH, Wp + (size_t)(8 + layer) * 65536, w, lane, acc);
  {
    float b0 = bu1[colL0], b1 = bu1[colL1];
#pragma unroll
    for (int rt = 0; rt < 4; ++rt)
#pragma unroll
      for (int reg = 0; reg < 4; ++reg) {
        acc[rt][0][reg] += b0;
        acc[rt][1][reg] += b1;
        float s = acc[rt][0][reg] + acc[rt][1][reg];
        float q = acc[rt][0][reg] * acc[rt][0][reg] + acc[rt][1][reg] * acc[rt][1][reg];
#pragma unroll
        for (int m = 8; m >= 1; m >>= 1) { s += __shfl_xor(s, m); q += __shfl_xor(q, m); }
        if (lol == 0) {
          int r = 16 * rt + 4 * g + reg;
          *reinterpret_cast<float2*>(lds + PART + (r * 4 + w) * 8) = make_float2(s, q);
        }
      }
  }
  __syncthreads();
  {
    float g0 = gu[colL0],  g1 = gu[colL1];
    float n0 = bun[colL0], n1 = bun[colL1];
#pragma unroll
    for (int rt = 0; rt < 4; ++rt)
#pragma unroll
      for (int reg = 0; reg < 4; ++reg) {
        int r = 16 * rt + 4 * g + reg;
        float S = 0.f, Q = 0.f;
#pragma unroll
        for (int wv = 0; wv < 4; ++wv) {
          float2 p = *reinterpret_cast<const float2*>(lds + PART + (r * 4 + wv) * 8);
          S += p.x; Q += p.y;
        }
        float mu   = S * (1.0f / 128.0f);
        float var  = Q * (1.0f / 128.0f) - mu * mu;
        float rstd = rsqrtf(var + 1e-5f);
        float v0 = fmaxf(0.f, (acc[rt][0][reg] - mu) * rstd * g0 + n0);
        float v1 = fmaxf(0.f, (acc[rt][1][reg] - mu) * rstd * g1 + n1);
        put_bf(lds, BH, r, 2 * colL0, v0);
        put_bf(lds, BH, r, 2 * colL1, v1);
      }
  }
  __syncthreads();

  // ---- P3: x_new = h2@Wu2 + bu2 -> global (+ Abuf for P4) ----
  zero_acc(acc);
  gemm_bf(lds, BH, Wp + (size_t)(12 + layer) * 65536, w, lane, acc);
  {
    float b0 = bu2[colL0], b1 = bu2[colL1];
#pragma unroll
    for (int rt = 0; rt < 4; ++rt)
#pragma unroll
      for (int reg = 0; reg < 4; ++reg) {
        int r  = 16 * rt + 4 * g + reg;
        int rg = row0 + r;
        float v0 = acc[rt][0][reg] + b0;
        float v1 = acc[rt][1][reg] + b1;
        if (rg < M) {
          xout[(size_t)rg * HIDC + colL0] = v0;
          xout[(size_t)rg * HIDC + colL1] = v1;
        }
        if (PQn != nullptr) {
          put_bf(lds, AH, r, 2 * colL0, v0);
          put_bf(lds, AH, r, 2 * colL1, v1);
        }
      }
  }

  // ---- P4 (layers 0..2): PQ_next = x_new @ Wm1_{l+1} ----
  if (PQn != nullptr) {
    __syncthreads();
    zero_acc(acc);
    gemm_bf(lds, AH, Wp + (size_t)(17 + layer) * 65536, w, lane, acc);   // Wm1top[l+1]
#pragma unroll
    for (int rt = 0; rt < 4; ++rt)
#pragma unroll
      for (int reg = 0; reg < 4; ++reg) {
        int rg = row0 + 16 * rt + 4 * g + reg;
        if (rg < M) {
          PQn[(size_t)rg * 256 + colL0] = acc[rt][0][reg];
          PQn[(size_t)rg * 256 + colL1] = acc[rt][1][reg];
        }
      }
    zero_acc(acc);
    gemm_bf(lds, AH, Wp + (size_t)(21 + layer) * 65536, w, lane, acc);   // Wm1bot[l+1]
#pragma unroll
    for (int rt = 0; rt < 4; ++rt)
#pragma unroll
      for (int reg = 0; reg < 4; ++reg) {
        int rg = row0 + 16 * rt + 4 * g + reg;
        if (rg < M) {
          PQn[(size_t)rg * 256 + 128 + colL0] = acc[rt][0][reg];
          PQn[(size_t)rg * 256 + 128 + colL1] = acc[rt][1][reg];
        }
      }
  }
}

// ---------------- launch ----------------

extern "C" void kernel_launch(void* const* d_in, const int* in_sizes, int n_in,
                              void* d_out, int out_size, void* d_ws, size_t ws_size,
                              hipStream_t stream)
{
  const float*  x_in = (const float*)d_in[0];
  const edge_t* ei   = (const edge_t*)d_in[1];
  const float*  Wm1  = (const float*)d_in[2];
  const float*  bm1  = (const float*)d_in[3];
  const float*  gm   = (const float*)d_in[4];
  const float*  bmn  = (const float*)d_in[5];
  const float*  Wm2  = (const float*)d_in[6];
  const float*  bm2  = (const float*)d_in[7];
  const float*  Wu1  = (const float*)d_in[8];
  const float*  bu1  = (const float*)d_in[9];
  const float*  gu   = (const float*)d_in[10];
  const float*  bun  = (const float*)d_in[11];
  const float*  Wu2  = (const float*)d_in[12];
  const float*  bu2  = (const float*)d_in[13];

  const int N = NNODES, E = NEDGES;

  char* ws = (char*)d_ws;
  float* PQ   = (float*)(ws + 0);            // 51,200,000
  float* Hb   = (float*)(ws + 51200000);     // 25,600,000 (aliases deg during CSR build)
  int*   deg  = (int*)  (ws + 51200000);
  float* xA   = (float*)(ws + 76800000);     // 25,600,000
  float* xB   = (float*)(ws + 102400000);    // 25,600,000
  int* row_ptr  = (int*)(ws + 128000000);    // (N+1)*4
  int* fill_ptr = (int*)(ws + 128200064);    // N*4
  int* adj      = (int*)(ws + 128400064);    // E*4 = 2,000,000
  char* Wp      = ws + 130400064;            // 24*65536 = 1,572,864
  int* bsum     = (int*)(ws + 131972928);    // 256*4
  int* boff     = (int*)(ws + 131973952);    // 256*4  (end ~132.0 MB)

  const int pqBlocks   = (N + TM - 1) / TM;          // 1563
  const int aggBlocks  = (N + 3) / 4;
  const int fusBlocks  = (N + 63) / 64;              // 782

  // CSR build + weight pre-pack (once per call)
  hipMemsetAsync(deg, 0, (size_t)N * 4, stream);
  count_kernel<<<(E + THREADS - 1) / THREADS, THREADS, 0, stream>>>(ei, deg, E);
  scan_part <<<SCAN_B, THREADS, 0, stream>>>(deg, bsum, N);
  scan_top  <<<1, SCAN_B, 0, stream>>>(bsum, boff);
  scan_write<<<SCAN_B, THREADS, 0, stream>>>(deg, boff, row_ptr, fill_ptr, N, E);
  fill_kernel<<<(E + THREADS - 1) / THREADS, THREADS, 0, stream>>>(ei, fill_ptr, adj, E);
  pack_w<<<(24 * 16384 + THREADS - 1) / THREADS, THREADS, 0, stream>>>(
      Wm1, Wm2, Wu1, Wu2, (unsigned short*)Wp);

  pq_kernel<<<pqBlocks, THREADS, 0, stream>>>(x_in, Wm1, PQ, N);

  const float* xc = x_in;
  float* xnext[4] = {xA, xB, xA, (float*)d_out};

  for (int l = 0; l < 4; ++l) {
    agg_kernel<<<aggBlocks, THREADS, 0, stream>>>(
        PQ, row_ptr, adj, bm1 + l * HIDC, gm + l * HIDC, bmn + l * HIDC, Hb, N);
    fused_mfma<<<fusBlocks, THREADS, 0, stream>>>(
        xc, Hb, row_ptr, Wp, l,
        bm2 + l * HIDC, bu1 + l * HIDC, gu + l * HIDC, bun + l * HIDC, bu2 + l * HIDC,
        xnext[l], (l < 3) ? PQ : nullptr, N);
    xc = xnext[l];
  }
}